// Round 1
// baseline (54.988 us; speedup 1.0000x reference)
//
#include <hip/hip_runtime.h>

// MSCA fused multi-scale depthwise conv chain, one workgroup per (b,c) plane.
// x:[8,256,64,64] f32 -> (attn_0, attn_1, attn_2) each [8,256,64,64] f32.

#define HH 64
#define WW 64
#define PLANE 4096
#define NPLANES 2048
#define NTOT (NPLANES * PLANE)   // 8388608 elements per output tensor

// LDS geometry (word strides chosen odd -> <=2-way bank conflicts)
#define S0 69   // x, padded +-2   : 68 rows
#define S1 71   // attn, padded +-3: 70 rows
#define S2 75   // a0x, col pad +-5: 64 rows
#define S3 65   // a0y, row pad +-5: 74 rows
#define SB 65   // unpadded reuse stride for a1x/a1y/a2x

#define P0_SZ (68 * S0)              // 4692
#define P1_SZ (70 * S1)              // 4970
#define P2_SZ (64 * S2)              // 4800
#define P3_SZ (74 * S3)              // 4810
#define LDS_WORDS (P0_SZ + P1_SZ + P2_SZ + P3_SZ)   // 19272 words = 77088 B

__global__ __launch_bounds__(256, 2)
void msca_fused(const float* __restrict__ x,
                const float* __restrict__ w0,   const float* __restrict__ b0,
                const float* __restrict__ w0_1, const float* __restrict__ b0_1,
                const float* __restrict__ w0_2, const float* __restrict__ b0_2,
                const float* __restrict__ w1_1, const float* __restrict__ b1_1,
                const float* __restrict__ w1_2, const float* __restrict__ b1_2,
                const float* __restrict__ w2_1, const float* __restrict__ b2_1,
                const float* __restrict__ w2_2, const float* __restrict__ b2_2,
                float* __restrict__ out)
{
    __shared__ float lds[LDS_WORDS];
    float* Px  = lds;                          // x (padded +-2), later a1y (SB)
    float* Pa  = lds + P0_SZ;                  // attn (padded +-3), later a1x (SB)
    float* P0x = lds + P0_SZ + P1_SZ;          // a0x (col pad 5), later a2x (SB)
    float* P0y = lds + P0_SZ + P1_SZ + P2_SZ;  // a0y (row pad 5)

    const int t     = threadIdx.x;
    const int plane = blockIdx.x;
    const int ch    = plane & 255;

    const float* xg = x + (size_t)plane * PLANE;
    float* o0 = out + (size_t)plane * PLANE;
    float* o1 = o0 + NTOT;
    float* o2 = o0 + 2 * (size_t)NTOT;

    // row mapping: thread owns row r, cols [j0, j0+16)
    const int r  = t >> 2;
    const int j0 = (t & 3) << 4;
    // col mapping: wave owns rows [i0, i0+16), lane owns column c
    const int c  = t & 63;
    const int i0 = (t >> 6) << 4;

    // ---- stage 0: issue global loads early, zero LDS, then commit x to LDS ----
    float xr[16];
    #pragma unroll
    for (int k = 0; k < 16; k++) xr[k] = xg[k * 256 + t];

    for (int k = t; k < LDS_WORDS; k += 256) lds[k] = 0.f;
    __syncthreads();

    #pragma unroll
    for (int k = 0; k < 16; k++) {
        int idx = k * 256 + t;
        Px[((idx >> 6) + 2) * S0 + (idx & 63) + 2] = xr[k];
    }
    __syncthreads();

    // ---- phase 1: attn = conv5x5(x) + b0   (row-mapped, pad-free) ----
    float attnR[16];
    {
        float w5[25];
        #pragma unroll
        for (int k = 0; k < 25; k++) w5[k] = w0[ch * 25 + k];
        const float bb = b0[ch];
        #pragma unroll
        for (int j = 0; j < 16; j++) attnR[j] = bb;
        #pragma unroll
        for (int dr = 0; dr < 5; dr++) {
            float rv[20];
            const int base = (r + dr) * S0 + j0;   // x[r+dr-2][j0-2 ..]
            #pragma unroll
            for (int dj = 0; dj < 20; dj++) rv[dj] = Px[base + dj];
            #pragma unroll
            for (int v = 0; v < 5; v++) {
                const float wt = w5[dr * 5 + v];
                #pragma unroll
                for (int j = 0; j < 16; j++) attnR[j] += wt * rv[j + v];
            }
        }
        const int wbase = (r + 3) * S1 + (j0 + 3);
        #pragma unroll
        for (int j = 0; j < 16; j++) Pa[wbase + j] = attnR[j];
    }
    __syncthreads();

    // ---- phase 2a: a0x = conv1x7(attn) + b0_1  (row-mapped; attn in regs) ----
    float a0xR[16];
    {
        float wt[7];
        #pragma unroll
        for (int k = 0; k < 7; k++) wt[k] = w0_1[ch * 7 + k];
        const float bb = b0_1[ch];
        float av[22];                                // attn[r][j0-3+dj]
        const int base = (r + 3) * S1 + j0;
        #pragma unroll
        for (int dj = 0; dj < 3; dj++)   av[dj] = Pa[base + dj];
        #pragma unroll
        for (int j = 0; j < 16; j++)     av[3 + j] = attnR[j];
        #pragma unroll
        for (int dj = 19; dj < 22; dj++) av[dj] = Pa[base + dj];
        #pragma unroll
        for (int j = 0; j < 16; j++) a0xR[j] = bb;
        #pragma unroll
        for (int v = 0; v < 7; v++) {
            const float ww = wt[v];
            #pragma unroll
            for (int j = 0; j < 16; j++) a0xR[j] += ww * av[j + v];
        }
        const int wbase = r * S2 + (j0 + 5);
        #pragma unroll
        for (int j = 0; j < 16; j++) P0x[wbase + j] = a0xR[j];
    }
    // ---- phase 2b: a0y = conv7x1(attn) + b0_2  (col-mapped) ----
    float a0yR[16];
    {
        float wt[7];
        #pragma unroll
        for (int k = 0; k < 7; k++) wt[k] = w0_2[ch * 7 + k];
        const float bb = b0_2[ch];
        float cv[22];                                // attn[i0-3+dk][c]
        #pragma unroll
        for (int dk = 0; dk < 22; dk++) cv[dk] = Pa[(i0 + dk) * S1 + (c + 3)];
        #pragma unroll
        for (int ii = 0; ii < 16; ii++) a0yR[ii] = bb;
        #pragma unroll
        for (int u = 0; u < 7; u++) {
            const float ww = wt[u];
            #pragma unroll
            for (int ii = 0; ii < 16; ii++) a0yR[ii] += ww * cv[ii + u];
        }
        const int wbase = (i0 + 5) * S3 + c;
        #pragma unroll
        for (int ii = 0; ii < 16; ii++) P0y[wbase + ii * S3] = a0yR[ii];
    }
    __syncthreads();

    // ---- phase 3: attn_0 store; a1x; a1y ----
    #pragma unroll
    for (int ii = 0; ii < 16; ii++) {                 // attn_0 (col-mapped, coalesced)
        float ax = P0x[(i0 + ii) * S2 + (c + 5)];
        o0[(i0 + ii) * WW + c] = ax * a0yR[ii];
    }
    float a1xR[16];
    {   // a1x = conv1x11(a0x) + b1_1 (row-mapped; a0x in regs, halo pad-free)
        float wt[11];
        #pragma unroll
        for (int k = 0; k < 11; k++) wt[k] = w1_1[ch * 11 + k];
        const float bb = b1_1[ch];
        float xv[26];                                 // a0x[r][j0-5+dj]
        const int base = r * S2 + j0;
        #pragma unroll
        for (int dj = 0; dj < 5; dj++)   xv[dj] = P0x[base + dj];
        #pragma unroll
        for (int j = 0; j < 16; j++)     xv[5 + j] = a0xR[j];
        #pragma unroll
        for (int dj = 21; dj < 26; dj++) xv[dj] = P0x[base + dj];
        #pragma unroll
        for (int j = 0; j < 16; j++) a1xR[j] = bb;
        #pragma unroll
        for (int v = 0; v < 11; v++) {
            const float ww = wt[v];
            #pragma unroll
            for (int j = 0; j < 16; j++) a1xR[j] += ww * xv[j + v];
        }
        const int wbase = r * SB + j0;
        #pragma unroll
        for (int j = 0; j < 16; j++) Pa[wbase + j] = a1xR[j];   // Pa reused: a1x
    }
    float a1yR[16];
    {   // a1y = conv11x1(a0y) + b1_2 (col-mapped; a0y in regs, halo pad-free)
        float wt[11];
        #pragma unroll
        for (int k = 0; k < 11; k++) wt[k] = w1_2[ch * 11 + k];
        const float bb = b1_2[ch];
        float yv[26];                                 // a0y[i0-5+dk][c]
        #pragma unroll
        for (int dk = 0; dk < 5; dk++)   yv[dk] = P0y[(i0 + dk) * S3 + c];
        #pragma unroll
        for (int ii = 0; ii < 16; ii++)  yv[5 + ii] = a0yR[ii];
        #pragma unroll
        for (int dk = 21; dk < 26; dk++) yv[dk] = P0y[(i0 + dk) * S3 + c];
        #pragma unroll
        for (int ii = 0; ii < 16; ii++) a1yR[ii] = bb;
        #pragma unroll
        for (int u = 0; u < 11; u++) {
            const float ww = wt[u];
            #pragma unroll
            for (int ii = 0; ii < 16; ii++) a1yR[ii] += ww * yv[ii + u];
        }
        #pragma unroll
        for (int ii = 0; ii < 16; ii++) Px[(i0 + ii) * SB + c] = a1yR[ii]; // Px reused: a1y
    }
    __syncthreads();

    // ---- phase 4: attn_1 store; a2x ----
    #pragma unroll
    for (int ii = 0; ii < 16; ii++) {                 // attn_1 (col-mapped, coalesced)
        float ax = Pa[(i0 + ii) * SB + c];
        o1[(i0 + ii) * WW + c] = ax * a1yR[ii];
    }
    {   // a2x = conv1x21(a1x) + b2_1 (row-mapped; guarded halo)
        float wt[21];
        #pragma unroll
        for (int k = 0; k < 21; k++) wt[k] = w2_1[ch * 21 + k];
        const float bb = b2_1[ch];
        float xv[36];                                 // a1x[r][j0-10+d]
        #pragma unroll
        for (int d = 0; d < 10; d++) {
            int col = j0 - 10 + d;
            xv[d] = (col >= 0) ? Pa[r * SB + col] : 0.f;
        }
        #pragma unroll
        for (int j = 0; j < 16; j++) xv[10 + j] = a1xR[j];
        #pragma unroll
        for (int d = 0; d < 10; d++) {
            int col = j0 + 16 + d;
            xv[26 + d] = (col < WW) ? Pa[r * SB + col] : 0.f;
        }
        float acc[16];
        #pragma unroll
        for (int j = 0; j < 16; j++) acc[j] = bb;
        #pragma unroll
        for (int v = 0; v < 21; v++) {
            const float ww = wt[v];
            #pragma unroll
            for (int j = 0; j < 16; j++) acc[j] += ww * xv[j + v];
        }
        const int wbase = r * SB + j0;
        #pragma unroll
        for (int j = 0; j < 16; j++) P0x[wbase + j] = acc[j];   // P0x reused: a2x
    }
    __syncthreads();

    // ---- phase 5: a2y (col-mapped, guarded halo); attn_2 store ----
    {
        float wt[21];
        #pragma unroll
        for (int k = 0; k < 21; k++) wt[k] = w2_2[ch * 21 + k];
        const float bb = b2_2[ch];
        float yv[36];                                 // a1y[i0-10+d][c]
        #pragma unroll
        for (int d = 0; d < 10; d++) {
            int rr = i0 - 10 + d;
            yv[d] = (rr >= 0) ? Px[rr * SB + c] : 0.f;
        }
        #pragma unroll
        for (int ii = 0; ii < 16; ii++) yv[10 + ii] = a1yR[ii];
        #pragma unroll
        for (int d = 0; d < 10; d++) {
            int rr = i0 + 16 + d;
            yv[26 + d] = (rr < HH) ? Px[rr * SB + c] : 0.f;
        }
        float acc[16];
        #pragma unroll
        for (int ii = 0; ii < 16; ii++) acc[ii] = bb;
        #pragma unroll
        for (int u = 0; u < 21; u++) {
            const float ww = wt[u];
            #pragma unroll
            for (int ii = 0; ii < 16; ii++) acc[ii] += ww * yv[ii + u];
        }
        #pragma unroll
        for (int ii = 0; ii < 16; ii++) {
            float ax = P0x[(i0 + ii) * SB + c];
            o2[(i0 + ii) * WW + c] = ax * acc[ii];
        }
    }
}

extern "C" void kernel_launch(void* const* d_in, const int* in_sizes, int n_in,
                              void* d_out, int out_size, void* d_ws, size_t ws_size,
                              hipStream_t stream) {
    msca_fused<<<NPLANES, 256, 0, stream>>>(
        (const float*)d_in[0],
        (const float*)d_in[1],  (const float*)d_in[2],
        (const float*)d_in[3],  (const float*)d_in[4],
        (const float*)d_in[5],  (const float*)d_in[6],
        (const float*)d_in[7],  (const float*)d_in[8],
        (const float*)d_in[9],  (const float*)d_in[10],
        (const float*)d_in[11], (const float*)d_in[12],
        (const float*)d_in[13], (const float*)d_in[14],
        (float*)d_out);
}

// Round 2
// 46.052 us; speedup vs baseline: 1.1940x; 1.1940x over previous
//
#include <hip/hip_runtime.h>

// MSCA fused multi-scale depthwise conv chain, one workgroup per (b,c) plane.
// x:[8,256,64,64] f32 -> (attn_0, attn_1, attn_2) each [8,256,64,64] f32.
//
// LDS: two regions with liveness coloring (barrier-separated handoffs):
//   R1: X (68x68, img row i -> (i+2)*68, col j -> j+2)  ->  A0Y (i*68+c) -> A2Y (i*68+c)
//   R2: ATT (i*68 + j)                                  ->  A1Y (i*68+c)
// Horizontal halos via DPP lane shifts (VALU), vertical halos via wave-uniform
// guarded reads. All row-window LDS reads/writes are aligned float4.

#define YS 68
#define R1_SZ 4624                 // 68 rows * 68
#define LDS_WORDS (R1_SZ + 4352)   // + 64*68  = 8976 words = 35904 B

__device__ __forceinline__ float dpp_prev(float v) {   // lane i <- lane i-1 (16-lane rows)
    return __int_as_float(__builtin_amdgcn_update_dpp(
        0, __float_as_int(v), 0x111, 0xF, 0xF, false));  // row_shr:1
}
__device__ __forceinline__ float dpp_next(float v) {   // lane i <- lane i+1
    return __int_as_float(__builtin_amdgcn_update_dpp(
        0, __float_as_int(v), 0x101, 0xF, 0xF, false));  // row_shl:1
}
__device__ __forceinline__ void ld4(const float* p, float* f) {
    float4 q = *(const float4*)p;
    f[0] = q.x; f[1] = q.y; f[2] = q.z; f[3] = q.w;
}
__device__ __forceinline__ void st4(float* p, float a, float b, float c, float d) {
    float4 q; q.x = a; q.y = b; q.z = c; q.w = d;
    *(float4*)p = q;
}

__global__ __launch_bounds__(256, 4)
void msca_fused(const float* __restrict__ x,
                const float* __restrict__ w0,   const float* __restrict__ b0,
                const float* __restrict__ w0_1, const float* __restrict__ b0_1,
                const float* __restrict__ w0_2, const float* __restrict__ b0_2,
                const float* __restrict__ w1_1, const float* __restrict__ b1_1,
                const float* __restrict__ w1_2, const float* __restrict__ b1_2,
                const float* __restrict__ w2_1, const float* __restrict__ b2_1,
                const float* __restrict__ w2_2, const float* __restrict__ b2_2,
                float* __restrict__ out)
{
    __shared__ __align__(16) float lds[LDS_WORDS];
    float* R1 = lds;            // X -> A0Y -> A2Y
    float* R2 = lds + R1_SZ;    // ATT -> A1Y

    const int t     = threadIdx.x;
    const int plane = blockIdx.x;
    const int ch    = plane & 255;
    const int r  = t >> 2;          // row-mapped: image row
    const int jg = t & 3;           // col-group
    const int j0 = jg << 4;         // first col of 16-col strip
    const int c  = t & 63;          // col-mapped: column
    const int i0 = (t >> 6) << 4;   // col-mapped: first of 16 rows (wave-uniform)

    const float* xg = x + (size_t)plane * 4096;
    float* o0 = out + (size_t)plane * 4096;
    float* o1 = o0 + 8388608;
    float* o2 = o1 + 8388608;

    // ---- stage 0: global x loads (row-mapped, float4), zero X halos, commit ----
    float xR[16];
    #pragma unroll
    for (int k = 0; k < 4; k++) ld4(&xg[r * 64 + j0 + 4 * k], &xR[4 * k]);

    // halo rows (buf rows 0,1,66,67): 272 words; side cols (words 0,1,66,67 per interior row)
    #pragma unroll
    for (int k0 = 0; k0 < 2; k0++) {
        int k = t + 256 * k0;
        if (k < 272) R1[k < 136 ? k : k + 4352] = 0.f;
    }
    if (t < 64) {
        int b = (t + 2) * YS;
        R1[b] = 0.f; R1[b + 1] = 0.f; R1[b + 66] = 0.f; R1[b + 67] = 0.f;
    }
    // commit x: cols j0..j0+15 -> words j0+2..j0+17 (2x float2 edges + 3x float4)
    {
        float* row = &R1[(r + 2) * YS];
        float2 e0; e0.x = xR[0];  e0.y = xR[1];  *(float2*)&row[j0 + 2]  = e0;
        st4(&row[j0 + 4],  xR[2],  xR[3],  xR[4],  xR[5]);
        st4(&row[j0 + 8],  xR[6],  xR[7],  xR[8],  xR[9]);
        st4(&row[j0 + 12], xR[10], xR[11], xR[12], xR[13]);
        float2 e1; e1.x = xR[14]; e1.y = xR[15]; *(float2*)&row[j0 + 16] = e1;
    }
    __syncthreads();   // B1

    // ---- P1: attn = conv5x5(x)+b0 (row-mapped; center row from regs+DPP) ----
    float attnR[16];
    {
        const float bb = b0[ch];
        #pragma unroll
        for (int j = 0; j < 16; j++) attnR[j] = bb;
        #pragma unroll
        for (int dr = 0; dr < 5; dr++) {
            float f[20];                       // f[w] = col j0-2+w
            if (dr == 2) {
                float e0 = dpp_prev(xR[14]), e1 = dpp_prev(xR[15]);
                float e2 = dpp_next(xR[0]),  e3 = dpp_next(xR[1]);
                f[0] = jg ? e0 : 0.f;  f[1] = jg ? e1 : 0.f;
                #pragma unroll
                for (int k = 0; k < 16; k++) f[2 + k] = xR[k];
                f[18] = (jg < 3) ? e2 : 0.f;  f[19] = (jg < 3) ? e3 : 0.f;
            } else {
                const float* row = &R1[(r + dr) * YS + j0];   // buf row = img row + dr - 2 + 2
                #pragma unroll
                for (int k = 0; k < 5; k++) ld4(&row[4 * k], &f[4 * k]);
            }
            #pragma unroll
            for (int v = 0; v < 5; v++) {
                const float ww = w0[ch * 25 + dr * 5 + v];
                #pragma unroll
                for (int j = 0; j < 16; j++) attnR[j] += ww * f[j + v];
            }
        }
        float* row = &R2[r * YS];
        st4(&row[j0],      attnR[0],  attnR[1],  attnR[2],  attnR[3]);
        st4(&row[j0 + 4],  attnR[4],  attnR[5],  attnR[6],  attnR[7]);
        st4(&row[j0 + 8],  attnR[8],  attnR[9],  attnR[10], attnR[11]);
        st4(&row[j0 + 12], attnR[12], attnR[13], attnR[14], attnR[15]);
    }
    __syncthreads();   // B2  (ATT ready; X fully read -> R1 free for A0Y)

    // ---- P2a: a0x = conv1x7(attn)+b0_1 (regs + DPP halos) ----
    float a0xR[16];
    {
        const float bb = b0_1[ch];
        float av[22];                          // av[w] = col j0-3+w
        float p13 = dpp_prev(attnR[13]), p14 = dpp_prev(attnR[14]), p15 = dpp_prev(attnR[15]);
        float n0  = dpp_next(attnR[0]),  n1  = dpp_next(attnR[1]),  n2  = dpp_next(attnR[2]);
        av[0] = jg ? p13 : 0.f;  av[1] = jg ? p14 : 0.f;  av[2] = jg ? p15 : 0.f;
        #pragma unroll
        for (int k = 0; k < 16; k++) av[3 + k] = attnR[k];
        av[19] = (jg < 3) ? n0 : 0.f;  av[20] = (jg < 3) ? n1 : 0.f;  av[21] = (jg < 3) ? n2 : 0.f;
        #pragma unroll
        for (int j = 0; j < 16; j++) a0xR[j] = bb;
        #pragma unroll
        for (int v = 0; v < 7; v++) {
            const float ww = w0_1[ch * 7 + v];
            #pragma unroll
            for (int j = 0; j < 16; j++) a0xR[j] += ww * av[j + v];
        }
    }
    // ---- P2b: a0y = conv7x1(attn)+b0_2 (col-mapped, guarded rows) ----
    float a0yR[16];
    {
        const float bb = b0_2[ch];
        float cv[22];                          // cv[d] = attn[i0+d-3][c]
        #pragma unroll
        for (int d = 0; d < 22; d++) {
            const int ir = i0 + d - 3;
            cv[d] = ((unsigned)ir <= 63u) ? R2[ir * YS + c] : 0.f;
        }
        #pragma unroll
        for (int ii = 0; ii < 16; ii++) a0yR[ii] = bb;
        #pragma unroll
        for (int u = 0; u < 7; u++) {
            const float ww = w0_2[ch * 7 + u];
            #pragma unroll
            for (int ii = 0; ii < 16; ii++) a0yR[ii] += ww * cv[ii + u];
        }
        #pragma unroll
        for (int ii = 0; ii < 16; ii++) R1[(i0 + ii) * YS + c] = a0yR[ii];   // A0Y
    }
    __syncthreads();   // B3  (A0Y ready; ATT fully read -> R2 free for A1Y)

    // ---- P3: store attn_0; a1x (regs+DPP); a1y (col, guarded) ----
    #pragma unroll
    for (int k = 0; k < 4; k++) {              // attn_0 = a0x * a0y (row-mapped)
        float f[4]; ld4(&R1[r * YS + j0 + 4 * k], f);
        st4(&o0[r * 64 + j0 + 4 * k],
            a0xR[4 * k] * f[0], a0xR[4 * k + 1] * f[1],
            a0xR[4 * k + 2] * f[2], a0xR[4 * k + 3] * f[3]);
    }
    float a1xR[16];
    {
        const float bb = b1_1[ch];
        float xv[26];                          // xv[w] = col j0-5+w
        #pragma unroll
        for (int d = 0; d < 5; d++) {
            float p = dpp_prev(a0xR[11 + d]);
            float n = dpp_next(a0xR[d]);
            xv[d]      = jg ? p : 0.f;
            xv[21 + d] = (jg < 3) ? n : 0.f;
        }
        #pragma unroll
        for (int k = 0; k < 16; k++) xv[5 + k] = a0xR[k];
        #pragma unroll
        for (int j = 0; j < 16; j++) a1xR[j] = bb;
        #pragma unroll
        for (int v = 0; v < 11; v++) {
            const float ww = w1_1[ch * 11 + v];
            #pragma unroll
            for (int j = 0; j < 16; j++) a1xR[j] += ww * xv[j + v];
        }
    }
    float a1yR[16];
    {
        const float bb = b1_2[ch];
        float yv[26];                          // yv[d] = a0y[i0-5+d][c]
        #pragma unroll
        for (int d = 0; d < 5; d++)  yv[d]      = i0        ? R1[(i0 - 5 + d) * YS + c]  : 0.f;
        #pragma unroll
        for (int k = 0; k < 16; k++) yv[5 + k]  = a0yR[k];
        #pragma unroll
        for (int d = 0; d < 5; d++)  yv[21 + d] = (i0 < 48) ? R1[(i0 + 16 + d) * YS + c] : 0.f;
        #pragma unroll
        for (int ii = 0; ii < 16; ii++) a1yR[ii] = bb;
        #pragma unroll
        for (int u = 0; u < 11; u++) {
            const float ww = w1_2[ch * 11 + u];
            #pragma unroll
            for (int ii = 0; ii < 16; ii++) a1yR[ii] += ww * yv[ii + u];
        }
        #pragma unroll
        for (int ii = 0; ii < 16; ii++) R2[(i0 + ii) * YS + c] = a1yR[ii];   // A1Y
    }
    __syncthreads();   // B4  (A1Y ready; A0Y fully read -> R1 free for A2Y)

    // ---- P4: store attn_1; a2x (regs+DPP); a2y (col, guarded) ----
    #pragma unroll
    for (int k = 0; k < 4; k++) {              // attn_1 = a1x * a1y (row-mapped)
        float f[4]; ld4(&R2[r * YS + j0 + 4 * k], f);
        st4(&o1[r * 64 + j0 + 4 * k],
            a1xR[4 * k] * f[0], a1xR[4 * k + 1] * f[1],
            a1xR[4 * k + 2] * f[2], a1xR[4 * k + 3] * f[3]);
    }
    float a2xR[16];
    {
        const float bb = b2_1[ch];
        float xv[36];                          // xv[w] = col j0-10+w
        #pragma unroll
        for (int d = 0; d < 10; d++) {
            float p = dpp_prev(a1xR[6 + d]);
            float n = dpp_next(a1xR[d]);
            xv[d]      = jg ? p : 0.f;
            xv[26 + d] = (jg < 3) ? n : 0.f;
        }
        #pragma unroll
        for (int k = 0; k < 16; k++) xv[10 + k] = a1xR[k];
        #pragma unroll
        for (int j = 0; j < 16; j++) a2xR[j] = bb;
        #pragma unroll
        for (int v = 0; v < 21; v++) {
            const float ww = w2_1[ch * 21 + v];
            #pragma unroll
            for (int j = 0; j < 16; j++) a2xR[j] += ww * xv[j + v];
        }
    }
    {
        const float bb = b2_2[ch];
        float yv[36];                          // yv[d] = a1y[i0-10+d][c]
        #pragma unroll
        for (int d = 0; d < 10; d++) yv[d]      = i0        ? R2[(i0 - 10 + d) * YS + c] : 0.f;
        #pragma unroll
        for (int k = 0; k < 16; k++) yv[10 + k] = a1yR[k];
        #pragma unroll
        for (int d = 0; d < 10; d++) yv[26 + d] = (i0 < 48) ? R2[(i0 + 16 + d) * YS + c] : 0.f;
        float a2yR[16];
        #pragma unroll
        for (int ii = 0; ii < 16; ii++) a2yR[ii] = bb;
        #pragma unroll
        for (int u = 0; u < 21; u++) {
            const float ww = w2_2[ch * 21 + u];
            #pragma unroll
            for (int ii = 0; ii < 16; ii++) a2yR[ii] += ww * yv[ii + u];
        }
        #pragma unroll
        for (int ii = 0; ii < 16; ii++) R1[(i0 + ii) * YS + c] = a2yR[ii];   // A2Y
    }
    __syncthreads();   // B5  (A2Y ready)

    // ---- P5: store attn_2 = a2x * a2y (row-mapped) ----
    #pragma unroll
    for (int k = 0; k < 4; k++) {
        float f[4]; ld4(&R1[r * YS + j0 + 4 * k], f);
        st4(&o2[r * 64 + j0 + 4 * k],
            a2xR[4 * k] * f[0], a2xR[4 * k + 1] * f[1],
            a2xR[4 * k + 2] * f[2], a2xR[4 * k + 3] * f[3]);
    }
}

extern "C" void kernel_launch(void* const* d_in, const int* in_sizes, int n_in,
                              void* d_out, int out_size, void* d_ws, size_t ws_size,
                              hipStream_t stream) {
    msca_fused<<<2048, 256, 0, stream>>>(
        (const float*)d_in[0],
        (const float*)d_in[1],  (const float*)d_in[2],
        (const float*)d_in[3],  (const float*)d_in[4],
        (const float*)d_in[5],  (const float*)d_in[6],
        (const float*)d_in[7],  (const float*)d_in[8],
        (const float*)d_in[9],  (const float*)d_in[10],
        (const float*)d_in[11], (const float*)d_in[12],
        (const float*)d_in[13], (const float*)d_in[14],
        (float*)d_out);
}